// Round 2
// baseline (6152.732 us; speedup 1.0000x reference)
//
#include <hip/hip_runtime.h>

// ---------------------------------------------------------------------------
// PAM (parallax attention) forward, MI355X. Round 2: fix centering axes.
//
// Shapes: B=2, C=64, 4C=256, H=W=256, WS=8 -> hn=wn=32, P=64, windows=2048.
// d_out = [out_left (2,64,256,256), out_right (2,64,256,256)] fp32 concat.
//
// Reference patchify applied to [b,h,w,c]-ordered gathered tensors via flat
// reinterpretation: element (p,q,c') of window (hn,wn) is at flat offset
// f = c'*65536 + hn*2048 + p*256 + wn*8 + q of the [h,w,c] buffer.
//
// Centering (reference .mean((4,5))): over (q, c) per (b,hn,wn,p) — 512
// elements — NOT over (p,q) per channel.  <-- round-1 bug, fixed here.
//
// Workspace (floats):
//   [0, 33554432)        y1 (conv1 output, one side at a time);
//                        later aliased: GK@0, GQ@8388608, Gxr@16777216, Gxl@25165824
//   [33554432, 41943040) Q
//   [41943040, 50331648) K
//   [50331648, 50332672) bn stats: [side][scale(256), shift(256)]
// ---------------------------------------------------------------------------

__global__ __launch_bounds__(256) void k_bnstats(
    const float* __restrict__ cat_l, const float* __restrict__ cat_r,
    const float* __restrict__ gamma, const float* __restrict__ beta,
    float* __restrict__ stats)
{
    int ch = blockIdx.x & 255;
    int side = blockIdx.x >> 8;
    const float* src = side ? cat_r : cat_l;
    int tid = threadIdx.x;
    float s = 0.f, s2 = 0.f;
    #pragma unroll
    for (int b = 0; b < 2; ++b) {
        const float* p = src + (size_t)b * 16777216 + (size_t)ch * 65536;
        for (int i = tid; i < 65536; i += 256) {
            float v = p[i];
            s += v; s2 += v * v;
        }
    }
    __shared__ float rs[256], rq[256];
    rs[tid] = s; rq[tid] = s2;
    __syncthreads();
    for (int off = 128; off > 0; off >>= 1) {
        if (tid < off) { rs[tid] += rs[tid + off]; rq[tid] += rq[tid + off]; }
        __syncthreads();
    }
    if (tid == 0) {
        float mean = rs[0] * (1.f / 131072.f);
        float var  = rq[0] * (1.f / 131072.f) - mean * mean;
        float rstd = rsqrtf(var + 1e-5f);
        float sc = gamma[ch] * rstd;
        stats[side * 512 + ch] = sc;
        stats[side * 512 + 256 + ch] = beta[ch] - mean * sc;
    }
}

// Grouped 3x3 conv (groups=4, 64ic -> 64oc per group), BN applied to input on
// the fly, bias + LeakyReLU(0.1) epilogue. Tile: 8h x 32w per block, one group.
__global__ __launch_bounds__(256) void k_conv1(
    const float* __restrict__ cat, const float* __restrict__ stats,
    const float* __restrict__ w1, const float* __restrict__ b1,
    float* __restrict__ y1)
{
    int blk = blockIdx.x;
    int wt = blk & 7;  blk >>= 3;
    int ht = blk & 31; blk >>= 5;
    int g  = blk & 3;  blk >>= 2;
    int b  = blk;
    int tid = threadIdx.x;
    int tw = tid & 31, th = tid >> 5;
    int h = ht * 8 + th, w = wt * 32 + tw;

    __shared__ float tile[10][36];
    float acc[64];
    #pragma unroll
    for (int oc = 0; oc < 64; ++oc) acc[oc] = b1[g * 64 + oc];

    const float* catg = cat + ((size_t)b * 256 + g * 64) * 65536;
    int h0 = ht * 8 - 1, w0 = wt * 32 - 1;

    for (int ic = 0; ic < 64; ++ic) {
        float sc = stats[g * 64 + ic];
        float sh = stats[256 + g * 64 + ic];
        const float* plane = catg + (size_t)ic * 65536;
        __syncthreads();
        for (int i = tid; i < 340; i += 256) {
            int r = i / 34, cc = i - r * 34;
            int hh = h0 + r, ww = w0 + cc;
            float v = 0.f;
            if ((unsigned)hh < 256u && (unsigned)ww < 256u)
                v = fmaf(plane[hh * 256 + ww], sc, sh);
            tile[r][cc] = v;
        }
        __syncthreads();
        float xv[9];
        #pragma unroll
        for (int kh = 0; kh < 3; ++kh)
            #pragma unroll
            for (int kw = 0; kw < 3; ++kw)
                xv[kh * 3 + kw] = tile[th + kh][tw + kw];
        const float* wic = w1 + (size_t)(g * 64) * 576 + (size_t)ic * 9;
        #pragma unroll
        for (int oc = 0; oc < 64; ++oc) {
            const float* wo = wic + (size_t)oc * 576;  // block-uniform -> s_load
            float s = acc[oc];
            #pragma unroll
            for (int k = 0; k < 9; ++k) s = fmaf(wo[k], xv[k], s);
            acc[oc] = s;
        }
    }
    float* yp = y1 + ((size_t)b * 256 + g * 64) * 65536 + h * 256 + w;
    #pragma unroll
    for (int oc = 0; oc < 64; ++oc) {
        float v = acc[oc];
        yp[(size_t)oc * 65536] = v > 0.f ? v : 0.1f * v;
    }
}

// Grouped 3x3 conv on y1 + bias + BN(cat) residual, then grouped 1x1 (64->16
// per group) producing Q (or K). Never materializes the 256-ch ResB output.
__global__ __launch_bounds__(256) void k_conv2(
    const float* __restrict__ y1, const float* __restrict__ cat,
    const float* __restrict__ stats,
    const float* __restrict__ w2, const float* __restrict__ b2,
    const float* __restrict__ pw, const float* __restrict__ pb,
    float* __restrict__ Qout)
{
    int blk = blockIdx.x;
    int wt = blk & 7;  blk >>= 3;
    int ht = blk & 31; blk >>= 5;
    int g  = blk & 3;  blk >>= 2;
    int b  = blk;
    int tid = threadIdx.x;
    int tw = tid & 31, th = tid >> 5;
    int h = ht * 8 + th, w = wt * 32 + tw;

    __shared__ float tile[10][36];
    float acc[64];
    #pragma unroll
    for (int oc = 0; oc < 64; ++oc) acc[oc] = b2[g * 64 + oc];

    const float* yg = y1 + ((size_t)b * 256 + g * 64) * 65536;
    int h0 = ht * 8 - 1, w0 = wt * 32 - 1;

    for (int ic = 0; ic < 64; ++ic) {
        const float* plane = yg + (size_t)ic * 65536;
        __syncthreads();
        for (int i = tid; i < 340; i += 256) {
            int r = i / 34, cc = i - r * 34;
            int hh = h0 + r, ww = w0 + cc;
            float v = 0.f;
            if ((unsigned)hh < 256u && (unsigned)ww < 256u)
                v = plane[hh * 256 + ww];
            tile[r][cc] = v;
        }
        __syncthreads();
        float xv[9];
        #pragma unroll
        for (int kh = 0; kh < 3; ++kh)
            #pragma unroll
            for (int kw = 0; kw < 3; ++kw)
                xv[kh * 3 + kw] = tile[th + kh][tw + kw];
        const float* wic = w2 + (size_t)(g * 64) * 576 + (size_t)ic * 9;
        #pragma unroll
        for (int oc = 0; oc < 64; ++oc) {
            const float* wo = wic + (size_t)oc * 576;
            float s = acc[oc];
            #pragma unroll
            for (int k = 0; k < 9; ++k) s = fmaf(wo[k], xv[k], s);
            acc[oc] = s;
        }
    }
    // residual: + BN(cat)
    const float* catp = cat + ((size_t)b * 256 + g * 64) * 65536 + h * 256 + w;
    #pragma unroll
    for (int oc = 0; oc < 64; ++oc) {
        float sc = stats[g * 64 + oc];
        float sh = stats[256 + g * 64 + oc];
        acc[oc] += fmaf(catp[(size_t)oc * 65536], sc, sh);
    }
    // grouped 1x1: oq = g*16 + j over this group's 64 channels
    float* qp = Qout + ((size_t)b * 64 + g * 16) * 65536 + h * 256 + w;
    #pragma unroll
    for (int j = 0; j < 16; ++j) {
        const float* wv = pw + (size_t)(g * 16 + j) * 64;
        float s = pb[g * 16 + j];
        #pragma unroll
        for (int ic2 = 0; ic2 < 64; ++ic2) s = fmaf(wv[ic2], acc[ic2], s);
        qp[(size_t)j * 65536] = s;
    }
}

// Horizontal disparity gathers, output in [b,h,w,c] layout (flat-index ready).
__global__ __launch_bounds__(256) void k_gather(
    const float* __restrict__ Kb, const float* __restrict__ Qb,
    const float* __restrict__ xr, const float* __restrict__ xl,
    const int* __restrict__ dl, const int* __restrict__ dr,
    float* __restrict__ GK, float* __restrict__ GQ,
    float* __restrict__ Gxr, float* __restrict__ Gxl)
{
    int blk = blockIdx.x;
    int h = blk & 255; blk >>= 8;
    int b = blk & 1;   blk >>= 1;
    int sel = blk;
    const float* src; float* dst; const int* dd; int r2l;
    if (sel == 0)      { src = Kb; dst = GK;  dd = dl; r2l = 1; }
    else if (sel == 1) { src = Qb; dst = GQ;  dd = dr; r2l = 0; }
    else if (sel == 2) { src = xr; dst = Gxr; dd = dl; r2l = 1; }
    else               { src = xl; dst = Gxl; dd = dr; r2l = 0; }
    const int* drow = dd + ((size_t)b * 256 + h) * 256;
    const float* sp = src + (size_t)b * 4194304 + h * 256;
    float* dp = dst + ((size_t)b * 256 + h) * 16384;
    int tid = threadIdx.x;
    for (int i = tid; i < 16384; i += 256) {
        int w = i >> 6, cc = i & 63;
        int d = drow[w];
        int wi = r2l ? (w - d < 0 ? 0 : w - d) : (w + d > 255 ? 255 : w + d);
        dp[i] = sp[(size_t)cc * 65536 + wi];
    }
}

// Per-window attention: score = patchA @ centered(sel)^T, softmax, @ x_sel,
// unpatchify + masked residual. One block per (dir, b, hn, wn).
__global__ __launch_bounds__(256) void k_attn(
    const float* __restrict__ Qb, const float* __restrict__ Kb,
    const float* __restrict__ GK, const float* __restrict__ GQ,
    const float* __restrict__ Gxr, const float* __restrict__ Gxl,
    const float* __restrict__ xl, const float* __restrict__ xr,
    const int* __restrict__ dl, const int* __restrict__ dr,
    float* __restrict__ out)
{
    int blk = blockIdx.x;
    int wn = blk & 31; blk >>= 5;
    int hn = blk & 31; blk >>= 5;
    int b  = blk & 1;  blk >>= 1;
    int dir = blk;  // 0: out_left, 1: out_right

    const float* Amat = dir ? Kb : Qb;
    const float* Bg   = dir ? GQ : GK;
    const float* Xg   = dir ? Gxl : Gxr;
    const float* base = dir ? xr : xl;
    const int*  dd    = dir ? dr : dl;
    float* op = out + (size_t)dir * 8388608;

    __shared__ float A[64][65];
    __shared__ float Bm[64][65];
    __shared__ float S[64][65];
    __shared__ float rowsum[64];
    __shared__ float pmean[8];

    int tid = threadIdx.x;
    // A[p1][cc] = Amat[b, cc, hn*8+pr, wn*8+qr]   (true patchify)
    size_t abase = (size_t)b * 4194304 + (size_t)(hn * 8) * 256 + wn * 8;
    for (int i = tid; i < 4096; i += 256) {
        int cc = i >> 6, p1 = i & 63;
        A[p1][cc] = Amat[abase + (size_t)cc * 65536 + (p1 >> 3) * 256 + (p1 & 7)];
    }
    // Bm[p2][cc] = G[b, f], f = cc*65536 + hn*2048 + p*256 + wn*8 + q (scrambled)
    size_t gbase = (size_t)b * 4194304 + hn * 2048 + wn * 8;
    for (int i = tid; i < 4096; i += 256) {
        int cc = i >> 6, p2 = i & 63;
        Bm[p2][cc] = Bg[gbase + (size_t)cc * 65536 + (p2 >> 3) * 256 + (p2 & 7)];
    }
    __syncthreads();
    // center: reference means over axes (q, c) per p -> pmean[p] over 512 elems
    if (tid < 64) {
        float s = 0.f;
        #pragma unroll 8
        for (int cc = 0; cc < 64; ++cc) s += Bm[tid][cc];
        rowsum[tid] = s;
    }
    __syncthreads();
    if (tid < 8) {
        float s = 0.f;
        #pragma unroll
        for (int q = 0; q < 8; ++q) s += rowsum[tid * 8 + q];
        pmean[tid] = s * (1.f / 512.f);
    }
    __syncthreads();
    for (int i = tid; i < 4096; i += 256) {
        int p2 = i >> 6, cc = i & 63;
        Bm[p2][cc] -= pmean[p2 >> 3];
    }
    __syncthreads();

    int tp = (tid >> 4) << 2;
    int tc = (tid & 15) << 2;
    {   // S = A @ Bm^T  (4x4 per thread)
        float accs[4][4] = {};
        for (int cc = 0; cc < 64; ++cc) {
            float av[4], bv[4];
            #pragma unroll
            for (int i = 0; i < 4; ++i) av[i] = A[tp + i][cc];
            #pragma unroll
            for (int j = 0; j < 4; ++j) bv[j] = Bm[tc + j][cc];
            #pragma unroll
            for (int i = 0; i < 4; ++i)
                #pragma unroll
                for (int j = 0; j < 4; ++j)
                    accs[i][j] = fmaf(av[i], bv[j], accs[i][j]);
        }
        #pragma unroll
        for (int i = 0; i < 4; ++i)
            #pragma unroll
            for (int j = 0; j < 4; ++j)
                S[tp + i][tc + j] = accs[i][j];
    }
    __syncthreads();
    if (tid < 64) {  // row softmax
        float m = -3.0e38f;
        #pragma unroll 8
        for (int j = 0; j < 64; ++j) m = fmaxf(m, S[tid][j]);
        float ssum = 0.f;
        #pragma unroll 8
        for (int j = 0; j < 64; ++j) {
            float e = __expf(S[tid][j] - m);
            S[tid][j] = e; ssum += e;
        }
        float inv = 1.f / ssum;
        #pragma unroll 8
        for (int j = 0; j < 64; ++j) S[tid][j] *= inv;
    }
    __syncthreads();
    // reload Bm <- x_sel (scrambled)
    for (int i = tid; i < 4096; i += 256) {
        int cc = i >> 6, p2 = i & 63;
        Bm[p2][cc] = Xg[gbase + (size_t)cc * 65536 + (p2 >> 3) * 256 + (p2 & 7)];
    }
    __syncthreads();
    {   // out = S @ X, unpatchify, masked residual
        float accs[4][4] = {};
        for (int p2 = 0; p2 < 64; ++p2) {
            float sv[4], xv[4];
            #pragma unroll
            for (int i = 0; i < 4; ++i) sv[i] = S[tp + i][p2];
            #pragma unroll
            for (int j = 0; j < 4; ++j) xv[j] = Bm[p2][tc + j];
            #pragma unroll
            for (int i = 0; i < 4; ++i)
                #pragma unroll
                for (int j = 0; j < 4; ++j)
                    accs[i][j] = fmaf(sv[i], xv[j], accs[i][j]);
        }
        #pragma unroll
        for (int i = 0; i < 4; ++i) {
            int p1 = tp + i;
            int h1 = hn * 8 + (p1 >> 3), w1 = wn * 8 + (p1 & 7);
            int d = dd[(size_t)b * 65536 + h1 * 256 + w1];
            float msk = dir ? ((w1 + d <= 255) ? 1.f : 0.f)
                            : ((w1 - d >= 0) ? 1.f : 0.f);
            #pragma unroll
            for (int j = 0; j < 4; ++j) {
                int ch = tc + j;
                size_t o = (size_t)b * 4194304 + (size_t)ch * 65536 + (size_t)h1 * 256 + w1;
                op[o] = fmaf(accs[i][j], msk, base[o]);
            }
        }
    }
}

extern "C" void kernel_launch(void* const* d_in, const int* in_sizes, int n_in,
                              void* d_out, int out_size, void* d_ws, size_t ws_size,
                              hipStream_t stream) {
    (void)in_sizes; (void)n_in; (void)out_size; (void)ws_size;
    const float* x_left  = (const float*)d_in[0];
    const float* x_right = (const float*)d_in[1];
    const float* cat_l   = (const float*)d_in[2];
    const float* cat_r   = (const float*)d_in[3];
    const int*   d_left  = (const int*)d_in[4];
    const int*   d_right = (const int*)d_in[5];
    const float* gamma   = (const float*)d_in[6];
    const float* beta    = (const float*)d_in[7];
    const float* rb_w1   = (const float*)d_in[8];
    const float* rb_b1   = (const float*)d_in[9];
    const float* rb_w2   = (const float*)d_in[10];
    const float* rb_b2   = (const float*)d_in[11];
    const float* bq_w    = (const float*)d_in[12];
    const float* bq_b    = (const float*)d_in[13];
    const float* bs_w    = (const float*)d_in[14];
    const float* bs_b    = (const float*)d_in[15];
    float* out = (float*)d_out;
    float* ws  = (float*)d_ws;

    float* y1    = ws;               // 33,554,432 floats (reused per side)
    float* GK    = ws;               // alias after y1 is dead
    float* GQ    = ws + 8388608;
    float* Gxr   = ws + 16777216;
    float* Gxl   = ws + 25165824;
    float* Qb    = ws + 33554432;
    float* Kb    = ws + 41943040;
    float* stats = ws + 50331648;    // [2][scale 256 | shift 256]

    k_bnstats<<<512, 256, 0, stream>>>(cat_l, cat_r, gamma, beta, stats);
    k_conv1<<<2048, 256, 0, stream>>>(cat_l, stats, rb_w1, rb_b1, y1);
    k_conv2<<<2048, 256, 0, stream>>>(y1, cat_l, stats, rb_w2, rb_b2, bq_w, bq_b, Qb);
    k_conv1<<<2048, 256, 0, stream>>>(cat_r, stats + 512, rb_w1, rb_b1, y1);
    k_conv2<<<2048, 256, 0, stream>>>(y1, cat_r, stats + 512, rb_w2, rb_b2, bs_w, bs_b, Kb);
    k_gather<<<2048, 256, 0, stream>>>(Kb, Qb, x_right, x_left, d_left, d_right,
                                       GK, GQ, Gxr, Gxl);
    k_attn<<<4096, 256, 0, stream>>>(Qb, Kb, GK, GQ, Gxr, Gxl,
                                     x_left, x_right, d_left, d_right, out);
}